// Round 7
// baseline (60.896 us; speedup 1.0000x reference)
//
#include <hip/hip_runtime.h>

// AffinitySideLoss: B=4, E=12, H=W=512, S=8 offsets, output = 1 float scalar.
// d_in[0] = input_ float32 [4,12,512,512]
// d_in[1] = target int32   [4,1,512,512]
// d_in[2] = offsets int32  [8,2]  (values in [-27,0))
// d_out   = float32 [1]
// d_ws    = per-block partials: float [16][2048]  (131,072 B)
//
// R7: e-major hot loop for deep memory-level parallelism. Per channel e we
// issue 1 center + 8 shifted f2 loads (8 distinct rows, all independent),
// unroll-2 over e -> ~18 independent dwordx2 in flight per wave. Border
// lanes (wsb<0: both f2 elements clamp to col 0) are fixed with a single
// v_cndmask instead of a divergent branch. Seg/dice epilogue after the loop
// keeps hot-loop VGPRs low for max waves/CU. No LDS, no barriers in loop.

typedef float f2  __attribute__((ext_vector_type(2)));
typedef float f2u __attribute__((ext_vector_type(2), aligned(4)));
typedef int   i2  __attribute__((ext_vector_type(2)));
typedef int   i2u __attribute__((ext_vector_type(2), aligned(4)));

#define HWSZ 262144   // 512*512
#define NE   12
#define NS   8
#define NBLK 2048     // 4 batches x 512 rows

__global__ __launch_bounds__(256) void affloss_main(
    const float* __restrict__ emb, const int* __restrict__ seg,
    const int* __restrict__ offs, float* __restrict__ partial) {
  // XCD-aware swizzle (bijective: 2048 % 8 == 0): contiguous 256-row band
  // per XCD so shifted rows (<=27 above) hit that XCD's L2.
  const int bid = blockIdx.x;
  const int nb  = (bid & 7) * (NBLK / 8) + (bid >> 3);

  const int h   = nb & 511;        // row, block-uniform
  const int b   = nb >> 9;         // batch 0..3, block-uniform
  const int tid = threadIdx.x;
  const int w2  = tid << 1;        // 0..510

  const float* embB = emb + (size_t)b * NE * HWSZ;
  const int*   segB = seg + (size_t)b * HWSZ;
  const int base = (h << 9) + w2;

  // Per-offset addressing, computed once. rowoff is block-uniform (SGPR);
  // colv/brd are per-lane. offs[] reads are uniform -> s_load.
  int rowoff[NS];                 // shifted row start (float index)
  int colv[NS];                   // clamped column (>=0)
  bool brd[NS];                   // border: both px clamp to col 0
  #pragma unroll
  for (int s = 0; s < NS; ++s) {
    const int oy = offs[2 * s];
    const int ox = offs[2 * s + 1];
    int hs = h + oy; hs = hs < 0 ? 0 : hs;   // replication clamp (top)
    rowoff[s] = hs << 9;
    const int wsb = w2 + ox;                 // in [-27, 509]
    brd[s]  = wsb < 0;
    colv[s] = wsb < 0 ? 0 : wsb;
  }

  f2 ssv[NS];
  #pragma unroll
  for (int s = 0; s < NS; ++s) ssv[s] = f2{0.f, 0.f};

  // Hot loop: 9 independent loads per e, no LDS, no barriers, no branches.
  #pragma unroll 2
  for (int e = 0; e < NE; ++e) {
    const float* embE = embB + e * HWSZ;
    const f2 ce = *reinterpret_cast<const f2*>(embE + base);
    #pragma unroll
    for (int s = 0; s < NS; ++s) {
      f2 sh = *reinterpret_cast<const f2u*>(embE + rowoff[s] + colv[s]);
      sh[1] = brd[s] ? sh[0] : sh[1];        // border: both elements = col 0
      const float d0 = ce[0] - sh[0];
      const float d1 = ce[1] - sh[1];
      ssv[s][0] = fmaf(d0, d0, ssv[s][0]);
      ssv[s][1] = fmaf(d1, d1, ssv[s][1]);
    }
  }

  // Epilogue: seg affinities + dice partial sums (all loads L2-hot).
  const i2 tc = *reinterpret_cast<const i2u*>(segB + base);
  float arr[16];                   // [0..7]=num, [8..15]=den
  #pragma unroll
  for (int s = 0; s < NS; ++s) {
    i2 ts = *reinterpret_cast<const i2u*>(segB + rowoff[s] + colv[s]);
    ts[1] = brd[s] ? ts[0] : ts[1];

    float nacc = 0.f, dacc = 0.f;
    #pragma unroll
    for (int j = 0; j < 2; ++j) {
      float ss = ssv[s][j];                    // >= 0 by construction
      float n  = __builtin_amdgcn_sqrtf(ss);   // sqrt(0)=0 covers the where()
      float r  = fmaxf(fmaf(n, -(1.0f / 3.0f), 1.0f), 0.0f); // clip((3-n)/3,0)
      float a  = fmaf(-r, r, 1.0f);            // affinity = 1 - r^2
      float ta = (tc[j] == ts[j]) ? 0.f : 1.f; // 1 - equality
      nacc = fmaf(a, ta, nacc);
      dacc += fmaf(a, a, ta);                  // a^2 + ta  (ta^2 == ta)
    }
    arr[s] = nacc;
    arr[8 + s] = dacc;
  }

  // wave (64-lane) shuffle reduction per channel
  #pragma unroll
  for (int k = 0; k < 16; ++k) {
    float v = arr[k];
    #pragma unroll
    for (int o = 32; o > 0; o >>= 1) v += __shfl_down(v, o, 64);
    arr[k] = v;
  }

  __shared__ float red[4][16];
  const int lane = tid & 63, wv = tid >> 6;
  if (lane == 0) {
    #pragma unroll
    for (int k = 0; k < 16; ++k) red[wv][k] = arr[k];
  }
  __syncthreads();
  if (tid < 16) {
    float v = red[0][tid] + red[1][tid] + red[2][tid] + red[3][tid];
    partial[tid * NBLK + blockIdx.x] = v;    // [channel][block]
  }
}

__global__ __launch_bounds__(1024) void affloss_final(
    const float* __restrict__ partial, float* __restrict__ out) {
  __shared__ double csum[16];
  const int lane = threadIdx.x & 63, wv = threadIdx.x >> 6;  // wv = channel 0..15

  double s = 0.0;
  for (int i = lane; i < NBLK; i += 64)
    s += (double)partial[wv * NBLK + i];
  #pragma unroll
  for (int o = 32; o > 0; o >>= 1) s += __shfl_down(s, o, 64);
  if (lane == 0) csum[wv] = s;
  __syncthreads();

  if (threadIdx.x == 0) {
    double total = 0.0;
    #pragma unroll
    for (int c = 0; c < 8; ++c) {
      double num = csum[c];
      double den = csum[8 + c];
      if (den < 1e-7) den = 1e-7;              // maximum(den, EPS)
      total += 1.0 - 2.0 * num / den;
    }
    out[0] = (float)total;
  }
}

extern "C" void kernel_launch(void* const* d_in, const int* in_sizes, int n_in,
                              void* d_out, int out_size, void* d_ws, size_t ws_size,
                              hipStream_t stream) {
  const float* emb  = (const float*)d_in[0];
  const int*   seg  = (const int*)d_in[1];
  const int*   offs = (const int*)d_in[2];
  float* partial = (float*)d_ws;   // 16*2048 floats = 131,072 B

  affloss_main<<<NBLK, 256, 0, stream>>>(emb, seg, offs, partial);
  affloss_final<<<1, 1024, 0, stream>>>(partial, (float*)d_out);
}